// Round 16
// baseline (1363.218 us; speedup 1.0000x reference)
//
#include <hip/hip_runtime.h>
#include <hip/hip_bf16.h>
#include <stdint.h>

typedef unsigned short u16;
typedef unsigned int   u32;
typedef float f32x4  __attribute__((ext_vector_type(4)));
typedef short bf16x8 __attribute__((ext_vector_type(8)));

#define NSEQ 800
#define TOUT 12
#define NC   9
#define LOG2E  1.44269504088896340736f
#define LOG2E2 2.88539008177792681472f

// ---- LDS (256-thread block = 4 waves = 4 gate-quarters, 16 seqs) ----
// Single-bf16 h state (RNE), ping-pong: PING@0, PONG@2048 (16 seq x 128 B row).
// k-map: k = n*4 + ht  (hid = ht*16+n); cell kq = k>>3 = n>>1, in-cell = (n&1)*8+ht*2.
// cell(seq,kq) @ seq*128 + rot*16, rot = (kq + seq + (seq>>3)) & 7.
// Reads (lane n, frag ks): kq = ks*4+q -> conflict-minimal b128; writes: b16, 4-way
// (structural floor: row stride 128B => bank entropy = n only).
// PRECISION NOTE (round 16): dropped lo-residual h. Error budget: bf16 weights ~1e-3
// + RNE h-quant random-walk ~1.2e-3 -> ~3-5e-3 vs 8.59e-3 threshold.
// REGISTER RULE (rounds 7-14): fits 3 waves/SIMD only; launch_bounds(256,3).
// Ping-pong buffers passed as constants via dual inlined call sites (no dynamic adds).
#define PONG 2048
#define VSCR 4096
#define LDS_TOTAL 4352

__device__ __forceinline__ u16 f2bf(float f){ union{float f;u32 i;}v; v.f=f; u32 x=v.i; return (u16)((x + 0x7fffu + ((x>>16)&1u))>>16); }
__device__ __forceinline__ u32 pkbf(float a, float b){
  union{ __hip_bfloat162 h2; u32 u; } v;
  v.h2 = __float22bfloat162_rn(float2{a,b});
  return v.u;
}

union BXU { uint4 u; bf16x8 v; };

__global__ __launch_bounds__(256, 3) void rnn_kernel(
  const float* __restrict__ X,
  const float* __restrict__ cw2, const float* __restrict__ cw3, const float* __restrict__ cw4,
  const float* __restrict__ cbv,
  const float* __restrict__ Ewih, const float* __restrict__ Ewhh,
  const float* __restrict__ Ebih, const float* __restrict__ Ebhh,
  const float* __restrict__ Dwih, const float* __restrict__ Dwhh,
  const float* __restrict__ Dbih, const float* __restrict__ Dbhh,
  const float* __restrict__ Lw,   const float* __restrict__ Lb,
  const float* __restrict__ emb,
  float* __restrict__ out)
{
  __shared__ char LDSC[LDS_TOTAL];
  const int tid = threadIdx.x;
  const int ht  = tid >> 6;      // wave id = gate-quarter
  const int l   = tid & 63;
  const int q   = l >> 4;
  const int n   = l & 15;
  const int r   = blockIdx.y;
  const int seqbase = blockIdx.x*16;
  const int hid = ht*16 + n;

  const int Kc[NC]={2,2,2,3,3,3,4,4,4};
  const int Dc[NC]={1,2,4,1,2,4,1,2,4};
  const int K = Kc[r], D = Dc[r];
  const int L = 15 - (K-1)*D;

  // zero PING (2048 B)
  if (tid < 128) *(uint4*)(LDSC + tid*16) = uint4{0,0,0,0};

  // ---- whh B-frags in registers (6 frags, k-mapped, exp2-scaled) ----
  // frag ks, element j: k = ks*32 + q*8 + j -> hid_src = ((j&3)<<4) | (ks*8 + q*2 + (j>>2))
  bf16x8 bhR[2], bhZ[2], bhN[2];
  auto gather_bh = [&](const float* __restrict__ whh){
    const float* pR = whh + (      hid)*64;
    const float* pZ = whh + ( 64 + hid)*64;
    const float* pN = whh + (128 + hid)*64;
    #pragma unroll
    for (int ks=0; ks<2; ks++){
      u32 wR[4]={0,0,0,0}, wZ[4]={0,0,0,0}, wN[4]={0,0,0,0};
      #pragma unroll
      for (int j=0;j<8;j++){
        int hh = ((j&3)<<4) | (ks*8 + q*2 + (j>>2));
        u32 sh = (u32)(j&1)*16;
        wR[j>>1] |= (u32)f2bf(LOG2E  * pR[hh]) << sh;
        wZ[j>>1] |= (u32)f2bf(LOG2E  * pZ[hh]) << sh;
        wN[j>>1] |= (u32)f2bf(LOG2E2 * pN[hh]) << sh;
      }
      BXU t;
      t.u = uint4{wR[0],wR[1],wR[2],wR[3]}; bhR[ks]=t.v;
      t.u = uint4{wZ[0],wZ[1],wZ[2],wZ[3]}; bhZ[ks]=t.v;
      t.u = uint4{wN[0],wN[1],wN[2],wN[3]}; bhN[ks]=t.v;
    }
  };
  gather_bh(Ewhh + (size_t)r*192*64);

  // ---- x B-frags (conv folded into wih), registers, exp2-scaled ----
  BXU bxR, bxZ, bxN;
  {
    const float* wih = Ewih + r*192*8;
    const float* cw  = (r<3) ? (cw2 + r*128) : (r<6) ? (cw3 + (r-3)*192) : (cw4 + (r-6)*256);
    bxR.u = uint4{0,0,0,0}; bxZ.u = uint4{0,0,0,0}; bxN.u = uint4{0,0,0,0};
    if (q < K){
      const float* rowR = wih + (      hid)*8;
      const float* rowZ = wih + ( 64 + hid)*8;
      const float* rowN = wih + (128 + hid)*8;
      u32 aR[4]={0,0,0,0}, aZ[4]={0,0,0,0}, aN[4]={0,0,0,0};
      #pragma unroll
      for (int j=0;j<8;j++){
        float sR=0.f,sZ=0.f,sN=0.f;
        #pragma unroll
        for (int o=0;o<8;o++){
          float c = cw[(o*8+j)*K + q];
          sR += rowR[o]*c; sZ += rowZ[o]*c; sN += rowN[o]*c;
        }
        u32 sh = (u32)(j&1)*16;
        aR[j>>1] |= (u32)f2bf(LOG2E *sR) << sh;
        aZ[j>>1] |= (u32)f2bf(LOG2E *sZ) << sh;
        aN[j>>1] |= (u32)f2bf(LOG2E2*sN) << sh;
      }
      bxR.u = uint4{aR[0],aR[1],aR[2],aR[3]};
      bxZ.u = uint4{aZ[0],aZ[1],aZ[2],aZ[3]};
      bxN.u = uint4{aN[0],aN[1],aN[2],aN[3]};
    }
  }

  // ---- biases (scaled), conv bias folded ----
  float bR, bZ, bNi, bNh_;
  {
    const float* bi = Ebih + r*192; const float* bh2 = Ebhh + r*192;
    const float* wih = Ewih + r*192*8; const float* cb = cbv + r*8;
    float cR=0.f,cZ=0.f,cN=0.f;
    #pragma unroll
    for (int o=0;o<8;o++){
      cR += wih[hid*8+o]*cb[o];
      cZ += wih[(64+hid)*8+o]*cb[o];
      cN += wih[(128+hid)*8+o]*cb[o];
    }
    bR  = LOG2E  * (bi[hid]     + bh2[hid]     + cR);
    bZ  = LOG2E  * (bi[64+hid]  + bh2[64+hid]  + cZ);
    bNi = LOG2E2 * (bi[128+hid]                + cN);
    bNh_= LOG2E2 *                bh2[128+hid];
  }

  float hO[4] = {0.f,0.f,0.f,0.f};

  // step-invariant LDS addresses
  const int ra0 = n*128 + (((  q + n + (n>>3))&7)<<4);
  const int ra1 = n*128 + (((4+q + n + (n>>3))&7)<<4);
  int wa[4];
  #pragma unroll
  for (int i=0;i<4;i++){
    int seq = q*4+i;
    wa[i] = seq*128 + ((((n>>1) + seq + (seq>>3))&7)<<4) + ((n&1)<<3) + (ht<<1);
  }

  // ---- one GRU step: read buf ro, write buf wo (compile-time-const offsets) ----
  auto step_core = [&](int ro, int wo, bf16x8 ax){
    const char* rp = LDSC + ro;
    bf16x8 a0 = *(const bf16x8*)(rp + ra0);
    bf16x8 a1 = *(const bf16x8*)(rp + ra1);
    f32x4 aR  = f32x4{bR,bR,bR,bR};
    f32x4 aZ  = f32x4{bZ,bZ,bZ,bZ};
    f32x4 aNi = f32x4{bNi,bNi,bNi,bNi};
    f32x4 aNh = f32x4{bNh_,bNh_,bNh_,bNh_};
    aR = __builtin_amdgcn_mfma_f32_16x16x32_bf16(a0, bhR[0], aR,0,0,0);
    aR = __builtin_amdgcn_mfma_f32_16x16x32_bf16(a1, bhR[1], aR,0,0,0);
    aR = __builtin_amdgcn_mfma_f32_16x16x32_bf16(ax, bxR.v,  aR,0,0,0);
    aZ = __builtin_amdgcn_mfma_f32_16x16x32_bf16(a0, bhZ[0], aZ,0,0,0);
    aZ = __builtin_amdgcn_mfma_f32_16x16x32_bf16(a1, bhZ[1], aZ,0,0,0);
    aZ = __builtin_amdgcn_mfma_f32_16x16x32_bf16(ax, bxZ.v,  aZ,0,0,0);
    aNh= __builtin_amdgcn_mfma_f32_16x16x32_bf16(a0, bhN[0], aNh,0,0,0);
    aNh= __builtin_amdgcn_mfma_f32_16x16x32_bf16(a1, bhN[1], aNh,0,0,0);
    aNi= __builtin_amdgcn_mfma_f32_16x16x32_bf16(ax, bxN.v,  aNi,0,0,0);
    char* wp = LDSC + wo;
    float hn[4];
    #pragma unroll
    for (int i=0;i<4;i++){
      float rr = __builtin_amdgcn_rcpf(1.f + __builtin_amdgcn_exp2f(-aR[i]));
      float zz = __builtin_amdgcn_rcpf(1.f + __builtin_amdgcn_exp2f(-aZ[i]));
      float y  = aNi[i] + rr*aNh[i];
      float nn = 1.f - 2.f*__builtin_amdgcn_rcpf(__builtin_amdgcn_exp2f(y) + 1.f);
      hn[i] = nn + zz*(hO[i]-nn);
      hO[i] = hn[i];
    }
    u32 p01 = pkbf(hn[0], hn[1]);
    u32 p23 = pkbf(hn[2], hn[3]);
    *(u16*)(wp + wa[0]) = (u16)p01;
    *(u16*)(wp + wa[1]) = (u16)(p01>>16);
    *(u16*)(wp + wa[2]) = (u16)p23;
    *(u16*)(wp + wa[3]) = (u16)(p23>>16);
  };

  // ---------- encoder: ping-pong, 1 barrier/step, unrolled x2 ----------
  const float* xb = X + (size_t)(seqbase + n)*120 + ((q<K)? q:0)*D*8;
  auto mk_a = [&](int t)->bf16x8{
    float4 v0 = *(const float4*)(xb + t*8);
    float4 v1 = *(const float4*)(xb + t*8 + 4);
    BXU a;
    a.u.x = __builtin_amdgcn_perm(__float_as_uint(v0.y), __float_as_uint(v0.x), 0x07060302u);
    a.u.y = __builtin_amdgcn_perm(__float_as_uint(v0.w), __float_as_uint(v0.z), 0x07060302u);
    a.u.z = __builtin_amdgcn_perm(__float_as_uint(v1.y), __float_as_uint(v1.x), 0x07060302u);
    a.u.w = __builtin_amdgcn_perm(__float_as_uint(v1.w), __float_as_uint(v1.z), 0x07060302u);
    return a.v;
  };
  __syncthreads();
  int t = 0;
  #pragma unroll 1
  for (; t+1<L; t+=2){
    step_core(0, PONG, mk_a(t));
    __syncthreads();
    step_core(PONG, 0, mk_a(t+1));
    __syncthreads();
  }
  if (t < L){
    step_core(0, PONG, mk_a(t));
    __syncthreads();
  }
  // final h in buf (L&1 ? PONG : PING)

  // ---------- decoder weight switch (registers only) ----------
  gather_bh(Dwhh + (size_t)r*192*64);
  {
    const float* dwih = Dwih + r*192;
    bxR.u = uint4{0,0,0,0}; bxZ.u = uint4{0,0,0,0}; bxN.u = uint4{0,0,0,0};
    if (q==0){
      bxR.u.x = (u32)f2bf(LOG2E *dwih[hid]);
      bxZ.u.x = (u32)f2bf(LOG2E *dwih[64+hid]);
      bxN.u.x = (u32)f2bf(LOG2E2*dwih[128+hid]);
    }
    const float* bi = Dbih + r*192; const float* bh2 = Dbhh + r*192;
    bR  = LOG2E  * (bi[hid]     + bh2[hid]);
    bZ  = LOG2E  * (bi[64+hid]  + bh2[64+hid]);
    bNi = LOG2E2 *  bi[128+hid];
    bNh_= LOG2E2 *  bh2[128+hid];
  }
  const float lwr = Lw[r*64 + hid];
  const float lb_ = Lb[r];
  float wgt;
  {
    int nb = (seqbase + n) % NSEQ;
    float e[NC], mx = -1e30f;
    #pragma unroll
    for (int c=0;c<NC;c++){ e[c] = emb[nb*NC+c]; mx = fmaxf(mx, e[c]); }
    float sm = 0.f;
    #pragma unroll
    for (int c=0;c<NC;c++) sm += __expf(e[c]-mx);
    wgt = __expf(e[r]-mx) / sm;
  }
  float lv = X[(size_t)(seqbase + n)*120 + 112];   // last0 for seq=n

  // ---------- decoder (2 barriers/step; buffers constant-propagated) ----------
  auto dec_step = [&](int t_, int ro, int wo){
    BXU a; a.u = uint4{0,0,0,0};
    if (q==0) a.u.x = (u32)f2bf(lv);
    step_core(ro, wo, a.v);
    float p0 = lwr*hO[0], p1 = lwr*hO[1], p2 = lwr*hO[2], p3 = lwr*hO[3];
    #pragma unroll
    for (int m=1; m<16; m<<=1){
      p0 += __shfl_xor(p0,m,64); p1 += __shfl_xor(p1,m,64);
      p2 += __shfl_xor(p2,m,64); p3 += __shfl_xor(p3,m,64);
    }
    __syncthreads();   // h-hazard + prior vs reads complete
    if (n==0){
      float* vs = (float*)(LDSC + VSCR);
      vs[ht*16 + q*4 + 0] = p0; vs[ht*16 + q*4 + 1] = p1;
      vs[ht*16 + q*4 + 2] = p2; vs[ht*16 + q*4 + 3] = p3;
    }
    __syncthreads();   // vs writes visible
    const float* vs = (const float*)(LDSC + VSCR);
    float v = vs[n] + vs[16+n] + vs[32+n] + vs[48+n] + lb_;
    lv = v;
    if (ht==0 && l<16) atomicAdd(out + (size_t)(seqbase+l)*TOUT + t_, wgt*v);
  };
  auto run_dec = [&](int c0, int c1){
    #pragma unroll 1
    for (int td=0; td<TOUT; td+=2){
      dec_step(td,   c0, c1);
      dec_step(td+1, c1, c0);
    }
  };
  if (L & 1) run_dec(PONG, 0);
  else       run_dec(0, PONG);
}

extern "C" void kernel_launch(void* const* d_in, const int* in_sizes, int n_in,
                              void* d_out, int out_size, void* d_ws, size_t ws_size,
                              hipStream_t stream)
{
  float* out = (float*)d_out;
  hipMemsetAsync(out, 0, (size_t)out_size*sizeof(float), stream);

  dim3 g(51200/16, NC);   // 3200 x 9 blocks; 16 seqs per block, 4 waves (gate-quarters)
  rnn_kernel<<<g, 256, 0, stream>>>(
    (const float*)d_in[1],
    (const float*)d_in[2], (const float*)d_in[3], (const float*)d_in[4],
    (const float*)d_in[5],
    (const float*)d_in[6], (const float*)d_in[7], (const float*)d_in[8], (const float*)d_in[9],
    (const float*)d_in[10],(const float*)d_in[11],(const float*)d_in[12],(const float*)d_in[13],
    (const float*)d_in[14],(const float*)d_in[15],
    (const float*)d_in[16],
    out);
}

// Round 17
// 995.671 us; speedup vs baseline: 1.3691x; 1.3691x over previous
//
#include <hip/hip_runtime.h>
#include <hip/hip_bf16.h>
#include <stdint.h>

typedef unsigned short u16;
typedef unsigned int   u32;
typedef float f32x4  __attribute__((ext_vector_type(4)));
typedef short bf16x8 __attribute__((ext_vector_type(8)));

#define NSEQ 800
#define TOUT 12
#define NC   9
#define LOG2E  1.44269504088896340736f
#define LOG2E2 2.88539008177792681472f

// ---- Round-17 structure: seq-split waves, NO in-loop barriers ----
// Block = 256 thr = 4 waves; wave wv owns seqs [blockIdx.x*64 + wv*16, +16) and ALL
// 192 gate-cols. h is wave-private (intra-wave program order => no __syncthreads in
// the recurrent loops; only 3 total for weight staging).
// LDS: BH @0: 24 groups (ks*12+nt) x 64 lanes x 16B = 24576 (whh B-frags, exp2-scaled)
//      BX @24576: 12 groups x 1024 = 12288 (conv-folded wih / dwih B-frags)
//      H  @36864: 4 waves x 2048 (16 seq x 128B; bf16 h in k-order)
// k-map: k = 4*n + ht  (hid = ht*16+n). cell(seq, k>>3) @ seq*128 + rot*16,
// rot = ((k>>3)+seq)&7; in-cell byte (k&7)*2. Reads (lane n,q; frag ks: cells ks*4+q)
// rotate by n => 2-way banks (free); writes: 4 b64/lane/step, exactly 4 phases (min).
// B-frag reads at (g*64+l)*16: stride-16 over 64 lanes = 2-way = free (m97 layout).
// REGISTER RULE (r7-14): fits 3 waves/SIMD only; launch_bounds(256,3).
#define BH_OFF 0
#define BX_OFF 24576
#define H_OFF  36864
#define LDS_TOTAL 45056

__device__ __forceinline__ u16 f2bf(float f){ union{float f;u32 i;}v; v.f=f; u32 x=v.i; return (u16)((x + 0x7fffu + ((x>>16)&1u))>>16); }
__device__ __forceinline__ u32 pkbf(float a, float b){
  union{ __hip_bfloat162 h2; u32 u; } v;
  v.h2 = __float22bfloat162_rn(float2{a,b});
  return v.u;
}

union BXU { uint4 u; bf16x8 v; };

__global__ __launch_bounds__(256, 3) void rnn_kernel(
  const float* __restrict__ X,
  const float* __restrict__ cw2, const float* __restrict__ cw3, const float* __restrict__ cw4,
  const float* __restrict__ cbv,
  const float* __restrict__ Ewih, const float* __restrict__ Ewhh,
  const float* __restrict__ Ebih, const float* __restrict__ Ebhh,
  const float* __restrict__ Dwih, const float* __restrict__ Dwhh,
  const float* __restrict__ Dbih, const float* __restrict__ Dbhh,
  const float* __restrict__ Lw,   const float* __restrict__ Lb,
  const float* __restrict__ emb,
  float* __restrict__ out)
{
  __shared__ char LDSC[LDS_TOTAL];
  const int tid = threadIdx.x;
  const int wv  = tid >> 6;      // wave id -> seq group
  const int l   = tid & 63;
  const int q   = l >> 4;
  const int n   = l & 15;
  const int r   = blockIdx.y;
  const int seqb = blockIdx.x*64 + wv*16;   // this wave's 16 seqs

  const int Kc[NC]={2,2,2,3,3,3,4,4,4};
  const int Dc[NC]={1,2,4,1,2,4,1,2,4};
  const int K = Kc[r], D = Dc[r];
  const int L = 15 - (K-1)*D;

  // zero own h slice (wave-private, no barrier needed for this)
  const int HB = H_OFF + wv*2048;
  *(uint4*)(LDSC + HB + l*32)      = uint4{0,0,0,0};
  *(uint4*)(LDSC + HB + l*32 + 16) = uint4{0,0,0,0};

  // ---- cooperative whh staging: B[k][col] = s*whh[col][hid(k)], hid(k)=(k&3)*16+(k>>2)
  auto stage_Bh = [&](const float* __restrict__ whh){
    #pragma unroll 1
    for (int it=0; it<6; it++){
      int slot = it*256 + tid;
      int g = slot >> 6, fl = slot & 63;
      int ks = g/12, nt = g%12;
      int col = nt*16 + (fl&15);
      float s = (nt<8) ? LOG2E : LOG2E2;
      u32 w[4] = {0,0,0,0};
      #pragma unroll
      for (int j=0;j<8;j++){
        int hid = ((j&3)<<4) | (ks*8 + (fl>>4)*2 + (j>>2));
        w[j>>1] |= (u32)f2bf(s * whh[col*64 + hid]) << ((j&1)*16);
      }
      *(uint4*)(LDSC + BH_OFF + slot*16) = uint4{w[0],w[1],w[2],w[3]};
    }
  };
  // ---- cooperative x staging (encoder: conv folded into wih; k = tap*8 + feat)
  auto stage_Bx_enc = [&](){
    const float* wih = Ewih + r*192*8;
    const float* cw  = (r<3) ? (cw2 + r*128) : (r<6) ? (cw3 + (r-3)*192) : (cw4 + (r-6)*256);
    #pragma unroll 1
    for (int it=0; it<3; it++){
      int slot = it*256 + tid;
      int g = slot >> 6, fl = slot & 63;
      int col = g*16 + (fl&15);
      int tap = fl>>4;
      float s = (g<8) ? LOG2E : LOG2E2;
      u32 w[4] = {0,0,0,0};
      if (tap < K){
        #pragma unroll
        for (int j=0;j<8;j++){
          float a = 0.f;
          #pragma unroll
          for (int o=0;o<8;o++) a += wih[col*8+o]*cw[(o*8+j)*K + tap];
          w[j>>1] |= (u32)f2bf(s*a) << ((j&1)*16);
        }
      }
      *(uint4*)(LDSC + BX_OFF + slot*16) = uint4{w[0],w[1],w[2],w[3]};
    }
  };
  auto stage_Bx_dec = [&](){
    const float* dwih = Dwih + r*192;
    #pragma unroll 1
    for (int it=0; it<3; it++){
      int slot = it*256 + tid;
      int g = slot >> 6, fl = slot & 63;
      int col = g*16 + (fl&15);
      float s = (g<8) ? LOG2E : LOG2E2;
      u32 w0 = ((fl>>4)==0) ? (u32)f2bf(s*dwih[col]) : 0u;
      *(uint4*)(LDSC + BX_OFF + slot*16) = uint4{w0,0,0,0};
    }
  };

  stage_Bh(Ewhh + (size_t)r*192*64);
  stage_Bx_enc();

  // ---- per-lane biases (4 ht, exp2-scaled, conv bias folded) ----
  float bR4[4], bZ4[4], bNi4[4], bNh4[4];
  {
    const float* bi = Ebih + r*192; const float* bh2 = Ebhh + r*192;
    const float* wih = Ewih + r*192*8; const float* cb = cbv + r*8;
    #pragma unroll
    for (int ht=0; ht<4; ht++){
      int hid = ht*16 + n;
      float cR=0.f,cZ=0.f,cN=0.f;
      #pragma unroll
      for (int o=0;o<8;o++){
        cR += wih[hid*8+o]*cb[o];
        cZ += wih[(64+hid)*8+o]*cb[o];
        cN += wih[(128+hid)*8+o]*cb[o];
      }
      bR4[ht]  = LOG2E  * (bi[hid]     + bh2[hid]     + cR);
      bZ4[ht]  = LOG2E  * (bi[64+hid]  + bh2[64+hid]  + cZ);
      bNi4[ht] = LOG2E2 * (bi[128+hid]                + cN);
      bNh4[ht] = LOG2E2 *                bh2[128+hid];
    }
  }

  float hO[4][4];
  #pragma unroll
  for (int ht=0;ht<4;ht++) for (int i=0;i<4;i++) hO[ht][i]=0.f;

  // step-invariant h addresses
  const int ra0 = HB + n*128 + (((  q + n)&7)<<4);
  const int ra1 = HB + n*128 + (((4+q + n)&7)<<4);
  int wa[4];
  #pragma unroll
  for (int i=0;i<4;i++){
    int seq = q*4+i;
    wa[i] = HB + seq*128 + ((((n>>1) + seq)&7)<<4) + ((n&1)<<3);
  }

  // ---- one GRU step: fully wave-local (h reads -> MFMA -> pointwise -> b64 writes)
  auto step_core = [&](bf16x8 ax){
    bf16x8 a0 = *(const bf16x8*)(LDSC + ra0);
    bf16x8 a1 = *(const bf16x8*)(LDSC + ra1);
    float hsv[4]; u32 pk01[4], pk23[4];
    #pragma unroll
    for (int ht=0; ht<4; ht++){
      bf16x8 bR0 = *(const bf16x8*)(LDSC + BH_OFF + ((      ht)*64 + l)*16);
      bf16x8 bR1 = *(const bf16x8*)(LDSC + BH_OFF + ((12  + ht)*64 + l)*16);
      bf16x8 bZ0 = *(const bf16x8*)(LDSC + BH_OFF + (( 4 + ht)*64 + l)*16);
      bf16x8 bZ1 = *(const bf16x8*)(LDSC + BH_OFF + ((16  + ht)*64 + l)*16);
      bf16x8 bN0 = *(const bf16x8*)(LDSC + BH_OFF + (( 8 + ht)*64 + l)*16);
      bf16x8 bN1 = *(const bf16x8*)(LDSC + BH_OFF + ((20  + ht)*64 + l)*16);
      bf16x8 xR  = *(const bf16x8*)(LDSC + BX_OFF + ((      ht)*64 + l)*16);
      bf16x8 xZ  = *(const bf16x8*)(LDSC + BX_OFF + (( 4 + ht)*64 + l)*16);
      bf16x8 xN  = *(const bf16x8*)(LDSC + BX_OFF + (( 8 + ht)*64 + l)*16);
      f32x4 aR  = f32x4{bR4[ht],bR4[ht],bR4[ht],bR4[ht]};
      f32x4 aZ  = f32x4{bZ4[ht],bZ4[ht],bZ4[ht],bZ4[ht]};
      f32x4 aNi = f32x4{bNi4[ht],bNi4[ht],bNi4[ht],bNi4[ht]};
      f32x4 aNh = f32x4{bNh4[ht],bNh4[ht],bNh4[ht],bNh4[ht]};
      aR = __builtin_amdgcn_mfma_f32_16x16x32_bf16(a0, bR0, aR,0,0,0);
      aR = __builtin_amdgcn_mfma_f32_16x16x32_bf16(a1, bR1, aR,0,0,0);
      aR = __builtin_amdgcn_mfma_f32_16x16x32_bf16(ax, xR,  aR,0,0,0);
      aZ = __builtin_amdgcn_mfma_f32_16x16x32_bf16(a0, bZ0, aZ,0,0,0);
      aZ = __builtin_amdgcn_mfma_f32_16x16x32_bf16(a1, bZ1, aZ,0,0,0);
      aZ = __builtin_amdgcn_mfma_f32_16x16x32_bf16(ax, xZ,  aZ,0,0,0);
      aNh= __builtin_amdgcn_mfma_f32_16x16x32_bf16(a0, bN0, aNh,0,0,0);
      aNh= __builtin_amdgcn_mfma_f32_16x16x32_bf16(a1, bN1, aNh,0,0,0);
      aNi= __builtin_amdgcn_mfma_f32_16x16x32_bf16(ax, xN,  aNi,0,0,0);
      #pragma unroll
      for (int i=0;i<4;i++){
        float rr = __builtin_amdgcn_rcpf(1.f + __builtin_amdgcn_exp2f(-aR[i]));
        float zz = __builtin_amdgcn_rcpf(1.f + __builtin_amdgcn_exp2f(-aZ[i]));
        float y  = aNi[i] + rr*aNh[i];
        float nn = 1.f - 2.f*__builtin_amdgcn_rcpf(__builtin_amdgcn_exp2f(y) + 1.f);
        float hn = nn + zz*(hO[ht][i]-nn);
        hO[ht][i] = hn;
        if (ht==0)      hsv[i] = hn;
        else if (ht==1) pk01[i] = pkbf(hsv[i], hn);
        else if (ht==2) hsv[i] = hn;
        else            pk23[i] = pkbf(hsv[i], hn);
      }
    }
    #pragma unroll
    for (int i=0;i<4;i++){
      uint2 wv2; wv2.x = pk01[i]; wv2.y = pk23[i];
      *(uint2*)(LDSC + wa[i]) = wv2;
    }
  };

  // ---------- encoder: NO barriers in loop ----------
  const float* xb = X + (size_t)(seqb + n)*120 + ((q<K)? q:0)*D*8;
  __syncthreads();   // staging visible
  #pragma unroll 1
  for (int t=0; t<L; t++){
    float4 v0 = *(const float4*)(xb + t*8);
    float4 v1 = *(const float4*)(xb + t*8 + 4);
    BXU a;
    a.u.x = __builtin_amdgcn_perm(__float_as_uint(v0.y), __float_as_uint(v0.x), 0x07060302u);
    a.u.y = __builtin_amdgcn_perm(__float_as_uint(v0.w), __float_as_uint(v0.z), 0x07060302u);
    a.u.z = __builtin_amdgcn_perm(__float_as_uint(v1.y), __float_as_uint(v1.x), 0x07060302u);
    a.u.w = __builtin_amdgcn_perm(__float_as_uint(v1.w), __float_as_uint(v1.z), 0x07060302u);
    step_core(a.v);
  }

  // ---------- decoder weight switch (2 barriers around restage) ----------
  __syncthreads();   // all waves done reading encoder B
  stage_Bh(Dwhh + (size_t)r*192*64);
  stage_Bx_dec();
  {
    const float* bi = Dbih + r*192; const float* bh2 = Dbhh + r*192;
    #pragma unroll
    for (int ht=0; ht<4; ht++){
      int hid = ht*16 + n;
      bR4[ht]  = LOG2E  * (bi[hid]     + bh2[hid]);
      bZ4[ht]  = LOG2E  * (bi[64+hid]  + bh2[64+hid]);
      bNi4[ht] = LOG2E2 *  bi[128+hid];
      bNh4[ht] = LOG2E2 *  bh2[128+hid];
    }
  }
  float lwr[4];
  #pragma unroll
  for (int ht=0; ht<4; ht++) lwr[ht] = Lw[r*64 + ht*16 + n];
  const float lb_ = Lb[r];
  float wgt;
  {
    int nb = (seqb + n) % NSEQ;
    float e[NC], mx = -1e30f;
    #pragma unroll
    for (int c=0;c<NC;c++){ e[c] = emb[nb*NC+c]; mx = fmaxf(mx, e[c]); }
    float sm = 0.f;
    #pragma unroll
    for (int c=0;c<NC;c++) sm += __expf(e[c]-mx);
    wgt = __expf(e[r]-mx) / sm;
  }
  float lv = X[(size_t)(seqb + n)*120 + 112];   // last0 for seq=n
  __syncthreads();   // dec staging visible

  // ---------- decoder: NO barriers in loop (wave-local reduce) ----------
  #pragma unroll 1
  for (int t=0; t<TOUT; t++){
    BXU a; a.u = uint4{0,0,0,0};
    if (q==0) a.u.x = (u32)f2bf(lv);
    step_core(a.v);
    float p[4];
    #pragma unroll
    for (int i=0;i<4;i++)
      p[i] = hO[0][i]*lwr[0] + hO[1][i]*lwr[1] + hO[2][i]*lwr[2] + hO[3][i]*lwr[3];
    #pragma unroll
    for (int m=1; m<16; m<<=1){
      #pragma unroll
      for (int i=0;i<4;i++) p[i] += __shfl_xor(p[i], m, 64);
    }
    // lane needs v[seq=n]: source lane (n>>2)*16 + (n&3), its p[n&3]
    float s0 = (n&2) ? p[2] : p[0];
    float s1 = (n&2) ? p[3] : p[1];
    float se = (n&1) ? s1 : s0;
    float v = __shfl(se, (n>>2)*16 + (n&3), 64) + lb_;
    lv = v;
    if (q==0) atomicAdd(out + (size_t)(seqb+n)*TOUT + t, wgt*v);
  }
}

extern "C" void kernel_launch(void* const* d_in, const int* in_sizes, int n_in,
                              void* d_out, int out_size, void* d_ws, size_t ws_size,
                              hipStream_t stream)
{
  float* out = (float*)d_out;
  hipMemsetAsync(out, 0, (size_t)out_size*sizeof(float), stream);

  dim3 g(NSEQ*64/64, NC);   // 800 x 9 blocks; 64 seqs/block, 4 seq-split waves
  rnn_kernel<<<g, 256, 0, stream>>>(
    (const float*)d_in[1],
    (const float*)d_in[2], (const float*)d_in[3], (const float*)d_in[4],
    (const float*)d_in[5],
    (const float*)d_in[6], (const float*)d_in[7], (const float*)d_in[8], (const float*)d_in[9],
    (const float*)d_in[10],(const float*)d_in[11],(const float*)d_in[12],(const float*)d_in[13],
    (const float*)d_in[14],(const float*)d_in[15],
    (const float*)d_in[16],
    out);
}